// Round 4
// baseline (403.738 us; speedup 1.0000x reference)
//
#include <hip/hip_runtime.h>
#include <hip/hip_bf16.h>
#include <hip/hip_fp16.h>

// MLPSCM round 13: re-rolled chunk loop (I-cache theory).
// R12 evidence: scm duration (172us) invariant to occupancy 2x, VALU work
// 1.6x, VGPR halving; all pipes <25% busy; blocks fully co-resident.
// => per-wave stall ~95%, structure-invariant: instruction fetch. The 15x
// inlined chunks + unrolled tails = 40-80KB straight-line text, zero I$
// reuse, 16 waves/CU at different PCs thrash the 32KB I$; every wave
// streams text from L2 (~200cy/64B line) ~ the whole 172us.
// Changes:
//  - g_WT2[k][plane][n][256]: all chunks padded to uniform K=256. Padded
//    rows multiply vf windows that are exactly zero at use time (future /
//    own-chunk nodes) -> +0.0, bit-identical. Uniform K => constant-trip
//    "#pragma unroll 8" t-loop with STATIC vf indices inside a
//    "#pragma unroll 1" runtime k-loop: hot body ~6KB, I$-resident, 15x reuse.
//  - vf[q][TT] update via 15-case switch (static indices per case).
//  - xpose: float4 reads + padded LDS tile (stride 108), float4 writes.
//  - everything else per R12 (32 samples/wave, 4 waves/SIMD, ws feature-major
//    X + xpose, wave_barrier, fast activations, hi/lo fp16 W planes).

typedef _Float16 half8 __attribute__((ext_vector_type(8)));
typedef float    f32x4 __attribute__((ext_vector_type(4)));

constexpr int S_LEN    = 131072;
constexpr int N_NODES  = 256;
constexpr int N_CAUSES = 16;
constexpr int N_COMP   = 240;
constexpr int N_FEAT   = 100;
constexpr float NOISE  = 0.01f;
constexpr float VSC    = 0.0625f;   // vals store scale 1/16
constexpr float VSCI   = 16.0f;

__device__ _Float16 g_WT2[15 * 2 * 16 * 256]; // [k-1][plane hi/lo][n][kk], 245760 B
__device__ float    g_Wtri[15 * 256];         // per chunk: [l][i] in-chunk triangular W

// ---------- content sniffers ----------
__device__ __forceinline__ bool sniff_binary64(const void* p) {
    const unsigned* u = (const unsigned*)p;
    bool ok = true;
    for (int i = 0; i < 64; ++i) ok = ok && (u[i] <= 1u);
    return ok;
}
__device__ __forceinline__ bool sniff_is_bf16(const void* p) {
    const unsigned* u = (const unsigned*)p;
    bool ok = true;
    for (int i = 0; i < 16; ++i) {
        unsigned e = ((u[i] << 16) >> 23) & 0xffu;
        ok = ok && (e >= 100u) && (e <= 132u);
    }
    return ok;
}
__device__ __forceinline__ float bflo(unsigned u) { return __uint_as_float(u << 16); }
__device__ __forceinline__ float bfhi(unsigned u) { return __uint_as_float(u & 0xffff0000u); }

__device__ __forceinline__ void load16(const void* base, long long off, bool isbf, float* o) {
    if (isbf) {
        const uint4* p = (const uint4*)((const unsigned short*)base + off);
        uint4 a = p[0], b = p[1];
        o[0]=bflo(a.x); o[1]=bfhi(a.x); o[2]=bflo(a.y); o[3]=bfhi(a.y);
        o[4]=bflo(a.z); o[5]=bfhi(a.z); o[6]=bflo(a.w); o[7]=bfhi(a.w);
        o[8]=bflo(b.x); o[9]=bfhi(b.x); o[10]=bflo(b.y); o[11]=bfhi(b.y);
        o[12]=bflo(b.z); o[13]=bfhi(b.z); o[14]=bflo(b.w); o[15]=bfhi(b.w);
    } else {
        const float4* p = (const float4*)((const float*)base + off);
        float4 x0=p[0], x1=p[1], x2=p[2], x3=p[3];
        o[0]=x0.x; o[1]=x0.y; o[2]=x0.z; o[3]=x0.w;
        o[4]=x1.x; o[5]=x1.y; o[6]=x1.z; o[7]=x1.w;
        o[8]=x2.x; o[9]=x2.y; o[10]=x2.z; o[11]=x2.w;
        o[12]=x3.x; o[13]=x3.y; o[14]=x3.z; o[15]=x3.w;
    }
}

// ---------- fast activations (raw HW transcendentals; err ~1e-7 rel) ----------
__device__ __forceinline__ float hw_exp2(float x) {
    float r; asm("v_exp_f32 %0, %1" : "=v"(r) : "v"(x)); return r;
}
__device__ __forceinline__ float hw_rcp(float x) {
    float r; asm("v_rcp_f32 %0, %1" : "=v"(r) : "v"(x)); return r;
}
__device__ __forceinline__ float fast_tanh(float x) {
    float t = hw_exp2(x * 2.88539008177792681f);
    return 1.0f - 2.0f * hw_rcp(t + 1.0f);
}
__device__ __forceinline__ float fast_sigmoid(float x) {
    return hw_rcp(1.0f + hw_exp2(x * -1.44269504088896341f));
}

// ---------- prep: pack W^T hi/lo fp16, K padded to 256, + fp32 triangular ----------
__global__ void prep_kernel(const void* __restrict__ A, const void* __restrict__ B) {
    __shared__ int s_mA, s_wbf;
    if (threadIdx.x == 0) {
        s_mA  = sniff_binary64(A) ? 1 : 0;
        s_wbf = sniff_is_bf16(s_mA ? B : A) ? 1 : 0;
    }
    __syncthreads();
    const int*  maskp = (const int*)(s_mA ? A : B);
    const void* Wp    = s_mA ? B : A;
    const int k = blockIdx.x + 1, j0 = 16 * k;
    const int tid = threadIdx.x;           // tid == kk (0..255), full column

    for (int n = 0; n < 16; ++n) {
        const int gi = tid * N_NODES + (j0 + n);
        float w = 0.0f;
        if (maskp[gi])
            w = s_wbf ? __bfloat162float(((const __hip_bfloat16*)Wp)[gi])
                      : ((const float*)Wp)[gi];
        const _Float16 hi = (_Float16)w;
        const _Float16 lo = (_Float16)(w - (float)hi);
        g_WT2[(k - 1) * 8192 + n * 256 + tid]        = hi;   // hi plane
        g_WT2[(k - 1) * 8192 + 4096 + n * 256 + tid] = lo;   // lo plane
    }
    {   // triangular in-chunk weights, fp32
        const int l = tid >> 4, i = tid & 15;
        const int gi = (j0 + l) * N_NODES + (j0 + i);
        float w = 0.0f;
        if (l < i && maskp[gi])
            w = s_wbf ? __bfloat162float(((const __hip_bfloat16*)Wp)[gi])
                      : ((const float*)Wp)[gi];
        g_Wtri[(k - 1) * 256 + tid] = w;
    }
}

#define MFMA16(a, b, c) __builtin_amdgcn_mfma_f32_16x16x32_f16((a), (b), (c), 0, 0, 0)

__global__ __launch_bounds__(64, 4)
void scm_kernel(const void* __restrict__ causes,
                const void* __restrict__ eps,
                const int* __restrict__ act_id,
                const void* __restrict__ xidx_raw,
                const int* __restrict__ yidx_raw,
                float* __restrict__ out,
                float* __restrict__ wsX,
                long long ybase) {
    __shared__ __align__(16) float    Zbuf[32 * 21];   // 2688 B
    __shared__ __align__(16) _Float16 stag[32 * 24];   // 1536 B
    __shared__ short xpos[N_COMP];                     // 480 B

    const int lane = threadIdx.x;
    const long long sg = (long long)blockIdx.x * 32 + lane;  // valid for lane<32

    for (int t = lane; t < N_COMP; t += 64) xpos[t] = -1;
    const unsigned long long* x64 = (const unsigned long long*)xidx_raw;
    const int*                x32 = (const int*)xidx_raw;
    const bool is64 = ((x64[0] >> 32) == 0ull);
    __builtin_amdgcn_wave_barrier();
    for (int f = lane; f < N_FEAT; f += 64) {
        const int ix = is64 ? (int)x64[f] : x32[f];
        xpos[ix - N_CAUSES] = (short)f;
    }
    __builtin_amdgcn_wave_barrier();
    const int yi  = yidx_raw[0];
    const bool cbf = sniff_is_bf16(causes);
    const bool ebf = sniff_is_bf16(eps);

    const int mrow = lane & 15;
    const int quad = lane >> 4;

    // vals in registers: vf[q][t], zero-initialized
    half8 vz;
    #pragma unroll
    for (int e = 0; e < 8; ++e) vz[e] = (_Float16)0.0f;
    half8 vf[2][8];
    #pragma unroll
    for (int q = 0; q < 2; ++q) {
        #pragma unroll
        for (int t = 0; t < 8; ++t) vf[q][t] = vz;
    }

    // causes (nodes 0..15) -> window 0, quads 0/1, via staging scatter
    if (lane < 32) {
        float cv[16];
        load16(causes, sg * (long long)N_CAUSES, cbf, cv);
        half8 c0, c1;
        #pragma unroll
        for (int i = 0; i < 8; ++i) {
            c0[i] = (_Float16)(cv[i] * VSC);
            c1[i] = (_Float16)(cv[8 + i] * VSC);
        }
        *(half8*)(stag + lane * 24)     = c0;
        *(half8*)(stag + lane * 24 + 8) = c1;
    }
    __builtin_amdgcn_wave_barrier();
    if (quad < 2) {
        #pragma unroll
        for (int q = 0; q < 2; ++q)
            vf[q][0] = *(const half8*)(stag + (q * 16 + mrow) * 24 + (quad << 3));
    }
    __builtin_amdgcn_wave_barrier();

    float* outX = out + sg * N_FEAT;
    float* outY = out + ybase;

    // vf-update scatter: nodes j0..j0+15 -> window TT, lane-quads HB,HB+1
    #define UPD(TT, HB)                                                        \
        if (quad == (HB) || quad == (HB) + 1) {                                \
            const int boff = (quad - (HB)) << 3;                               \
            vf[0][TT] = *(const half8*)(stag + mrow * 24 + boff);              \
            vf[1][TT] = *(const half8*)(stag + (16 + mrow) * 24 + boff);       \
        }

    #pragma unroll 1
    for (int k = 1; k <= 15; ++k) {
        const int j0 = k << 4;

        // eps for this chunk (consumed in tail -> latency hidden under MFMAs)
        float ev[16];
        if (lane < 32)
            load16(eps, sg * (long long)N_COMP + (j0 - N_CAUSES), ebf, ev);

        const _Float16* __restrict__ bp =
            g_WT2 + (k - 1) * 8192 + mrow * 256 + (quad << 3);

        f32x4 acc0h = {0.f,0.f,0.f,0.f}, acc0l = {0.f,0.f,0.f,0.f};
        f32x4 acc1h = {0.f,0.f,0.f,0.f}, acc1l = {0.f,0.f,0.f,0.f};

        #pragma unroll
        for (int t = 0; t < 8; ++t) {                 // uniform K=256 (padded)
            const half8 bh = *(const half8*)(bp + (t << 5));
            const half8 bl = *(const half8*)(bp + 4096 + (t << 5));
            acc0h = MFMA16(vf[0][t], bh, acc0h);      // 4 independent chains
            acc1h = MFMA16(vf[1][t], bh, acc1h);
            acc0l = MFMA16(vf[0][t], bl, acc0l);
            acc1l = MFMA16(vf[1][t], bl, acc1l);
        }

        // C-layout (col=mrow = node, row=quad*4+reg = sample) -> Zbuf
        {
            const int r0 = quad << 2;
            #pragma unroll
            for (int r = 0; r < 4; ++r) {
                Zbuf[(r0 + r)      * 21 + mrow] = (acc0h[r] + acc0l[r]) * VSCI;
                Zbuf[(16 + r0 + r) * 21 + mrow] = (acc1h[r] + acc1l[r]) * VSCI;
            }
        }
        __builtin_amdgcn_wave_barrier();   // single-wave block: LDS in-order

        // intra-chunk tail, scatter form: sample = lane (lanes 0..31)
        if (lane < 32) {
            float zz[16];
            #pragma unroll
            for (int i = 0; i < 16; ++i)
                zz[i] = Zbuf[lane * 21 + i] + NOISE * ev[i];

            const float* __restrict__ tri = g_Wtri + (k - 1) * 256;
            half8 h0, h1;
            #pragma unroll
            for (int i = 0; i < 16; ++i) {
                float z = zz[i];
                const int a = act_id[j0 - N_CAUSES + i];   // wave-uniform
                if (a == 1)      z = fast_tanh(z);
                else if (a == 2) z = fmaxf(z, 0.0f);
                else if (a == 3) z = fast_sigmoid(z);
                if (i < 8) h0[i] = (_Float16)(z * VSC);
                else       h1[i - 8] = (_Float16)(z * VSC);
                const int xp = xpos[j0 - N_CAUSES + i];    // wave-uniform
                if (xp >= 0) {
                    if (wsX) wsX[(long long)xp * S_LEN + sg] = z;  // coalesced
                    else     outX[xp] = z;                         // fallback
                }
                if (j0 + i == yi) outY[sg] = z;
                // independent forward updates (same summation order as gather)
                #pragma unroll
                for (int j = i + 1; j < 16; ++j)
                    zz[j] += tri[(i << 4) + j] * z;
            }
            *(half8*)(stag + lane * 24)     = h0;
            *(half8*)(stag + lane * 24 + 8) = h1;
        }
        __builtin_amdgcn_wave_barrier();

        // scatter new 16 node-values into the A-fragment register layout
        switch (k) {
            case  1: UPD(0, 2); break;
            case  2: UPD(1, 0); break;
            case  3: UPD(1, 2); break;
            case  4: UPD(2, 0); break;
            case  5: UPD(2, 2); break;
            case  6: UPD(3, 0); break;
            case  7: UPD(3, 2); break;
            case  8: UPD(4, 0); break;
            case  9: UPD(4, 2); break;
            case 10: UPD(5, 0); break;
            case 11: UPD(5, 2); break;
            case 12: UPD(6, 0); break;
            case 13: UPD(6, 2); break;
            case 14: UPD(7, 0); break;
            case 15: UPD(7, 2); break;
        }
        __builtin_amdgcn_wave_barrier();
    }
    #undef UPD
}

// ---------- transpose: ws[100][S] -> out[S][100], float4 both sides ----------
__global__ __launch_bounds__(256)
void xpose_kernel(const float* __restrict__ ws, float* __restrict__ out) {
    __shared__ float tile[64 * 108];   // padded stride 108 (16B-aligned rows, ~2-way banks)
    const int tid = threadIdx.x;
    const long long s0 = (long long)blockIdx.x * 64;
    // read: 100 features x 16 float4-groups = 1600 float4 (4 samples each)
    #pragma unroll
    for (int g = 0; g < 7; ++g) {
        const int idx = g * 256 + tid;
        if (idx < 1600) {
            const int ff = idx >> 4;       // feature 0..99
            const int sl = idx & 15;       // sample-group
            const float4 v = *(const float4*)(ws + (long long)ff * S_LEN + s0 + sl * 4);
            tile[(sl * 4 + 0) * 108 + ff] = v.x;
            tile[(sl * 4 + 1) * 108 + ff] = v.y;
            tile[(sl * 4 + 2) * 108 + ff] = v.z;
            tile[(sl * 4 + 3) * 108 + ff] = v.w;
        }
    }
    __syncthreads();
    // write: 64 samples x 25 float4 = 1600 float4, contiguous 400B runs
    #pragma unroll
    for (int g = 0; g < 7; ++g) {
        const int idx = g * 256 + tid;
        if (idx < 1600) {
            const int s = idx / 25;
            const int j = idx % 25;
            const float4 v = *(const float4*)(tile + s * 108 + j * 4);
            *(float4*)(out + (s0 + s) * N_FEAT + j * 4) = v;
        }
    }
}

extern "C" void kernel_launch(void* const* d_in, const int* in_sizes, int n_in,
                              void* d_out, int out_size, void* d_ws, size_t ws_size,
                              hipStream_t stream) {
    // resolve inputs by element count (permutation-proof); fall back to dict order
    int ic = 0, iw = 1, ie = 2, im = 3, ia = 4, ix = 5, iy = 6;
    int c = -1, e = -1, a = -1, x = -1, y = -1, m1 = -1, m2 = -1;
    for (int i = 0; i < n_in; ++i) {
        switch (in_sizes[i]) {
            case S_LEN * N_CAUSES:   c = i; break;
            case S_LEN * N_COMP:     e = i; break;
            case N_COMP:             a = i; break;
            case N_FEAT:             x = i; break;
            case 1:                  y = i; break;
            case N_NODES * N_NODES:  (m1 < 0 ? m1 : m2) = i; break;
        }
    }
    if (c >= 0 && e >= 0 && a >= 0 && x >= 0 && y >= 0 && m1 >= 0 && m2 >= 0) {
        ic = c; ie = e; ia = a; ix = x; iy = y; iw = m1; im = m2;
    }

    const void* causes = d_in[ic];
    const void* TA     = d_in[iw];   // one of {W, mask} — device disambiguates
    const void* TB     = d_in[im];
    const void* eps    = d_in[ie];
    const int*  act_id = (const int*)d_in[ia];
    const void* xidx   = d_in[ix];
    const int*  yidx   = (const int*)d_in[iy];
    float*      out    = (float*)d_out;
    const long long ybase = (long long)out_size - S_LEN;

    const bool usews = ws_size >= (size_t)N_FEAT * S_LEN * sizeof(float);
    float* wsX = usews ? (float*)d_ws : nullptr;

    prep_kernel<<<15, 256, 0, stream>>>(TA, TB);
    scm_kernel<<<S_LEN / 32, 64, 0, stream>>>(causes, eps, act_id, xidx, yidx,
                                              out, wsX, ybase);
    if (usews)
        xpose_kernel<<<S_LEN / 64, 256, 0, stream>>>(wsX, out);
}

// Round 5
// 386.222 us; speedup vs baseline: 1.0454x; 1.0454x over previous
//
#include <hip/hip_runtime.h>
#include <hip/hip_bf16.h>
#include <hip/hip_fp16.h>

// MLPSCM round 14: barrier-free single-wave chunks + branch-free tail.
// R13 post-mortem: I-cache theory dead (smaller text, MORE time; time tracked
// the padded extra work). Model now: wall time = per-wave critical path
// (all blocks co-resident), ~95% latency bubbles. Serializers:
//  (1) wave_barrier = full compiler scheduling fence -> each chunk sealed,
//      no overlap of chunk k+1 loads/MFMAs with chunk k tail;
//  (2) ~80 wave-uniform branches per chunk in the tail (act/xp/yi), each a
//      s_cbranch bubble.
// Changes (single-wave blocks make barriers unnecessary; LDS is in-order
// within a wave and may-alias ordering preserves Zbuf/stag RAW):
//  - ALL wave_barriers removed; R12 exact-KE fully-inlined structure kept.
//  - branch-free activations: compute tanh/relu/sigmoid always, select via
//    cndmask (bit-identical: same selected expression as before).
//  - branch-free stores: meta[n] = act | dst<<2 in LDS (dst: 0..99=X row,
//    100=y row, 101=trash row); tail stores every node unconditionally to
//    ws[dst*S+sg] (coalesced). xpose copies y row to out[ybase..].
//  - ws needs 102 rows = 53.5MB (guarded; legacy branchy fallback kept).

typedef _Float16 half8 __attribute__((ext_vector_type(8)));
typedef float    f32x4 __attribute__((ext_vector_type(4)));

constexpr int S_LEN    = 131072;
constexpr int N_NODES  = 256;
constexpr int N_CAUSES = 16;
constexpr int N_COMP   = 240;
constexpr int N_FEAT   = 100;
constexpr float NOISE  = 0.01f;
constexpr float VSC    = 0.0625f;   // vals store scale 1/16
constexpr float VSCI   = 16.0f;

constexpr int ROW_Y  = 100;   // ws row for y
constexpr int ROW_TR = 101;   // ws trash row
constexpr int WS_ROWS = 102;

// K_eff per chunk (K=16k+16 rounded up to 32) and hi/lo-plane pack offsets
constexpr int KE_tab[16]  = {0,32,64,64,96,96,128,128,160,160,192,192,224,224,256,256};
constexpr int OFF_tab[16] = {0,0,1024,3072,5120,8192,11264,15360,19456,24576,29696,
                             35840,41984,49152,56320,64512};

__constant__ int c_KE[16]  = {0,32,64,64,96,96,128,128,160,160,192,192,224,224,256,256};
__constant__ int c_OFF[16] = {0,0,1024,3072,5120,8192,11264,15360,19456,24576,29696,
                              35840,41984,49152,56320,64512};

__device__ _Float16 g_WT[72704];      // per chunk: [hi|lo] planes of [16 cols][KE] W^T
__device__ float    g_Wtri[15 * 256]; // per chunk: [l][i] in-chunk triangular W (fp32)

// ---------- content sniffers ----------
__device__ __forceinline__ bool sniff_binary64(const void* p) {
    const unsigned* u = (const unsigned*)p;
    bool ok = true;
    for (int i = 0; i < 64; ++i) ok = ok && (u[i] <= 1u);
    return ok;
}
__device__ __forceinline__ bool sniff_is_bf16(const void* p) {
    const unsigned* u = (const unsigned*)p;
    bool ok = true;
    for (int i = 0; i < 16; ++i) {
        unsigned e = ((u[i] << 16) >> 23) & 0xffu;
        ok = ok && (e >= 100u) && (e <= 132u);
    }
    return ok;
}
__device__ __forceinline__ float bflo(unsigned u) { return __uint_as_float(u << 16); }
__device__ __forceinline__ float bfhi(unsigned u) { return __uint_as_float(u & 0xffff0000u); }

__device__ __forceinline__ void load16(const void* base, long long off, bool isbf, float* o) {
    if (isbf) {
        const uint4* p = (const uint4*)((const unsigned short*)base + off);
        uint4 a = p[0], b = p[1];
        o[0]=bflo(a.x); o[1]=bfhi(a.x); o[2]=bflo(a.y); o[3]=bfhi(a.y);
        o[4]=bflo(a.z); o[5]=bfhi(a.z); o[6]=bflo(a.w); o[7]=bfhi(a.w);
        o[8]=bflo(b.x); o[9]=bfhi(b.x); o[10]=bflo(b.y); o[11]=bfhi(b.y);
        o[12]=bflo(b.z); o[13]=bfhi(b.z); o[14]=bflo(b.w); o[15]=bfhi(b.w);
    } else {
        const float4* p = (const float4*)((const float*)base + off);
        float4 x0=p[0], x1=p[1], x2=p[2], x3=p[3];
        o[0]=x0.x; o[1]=x0.y; o[2]=x0.z; o[3]=x0.w;
        o[4]=x1.x; o[5]=x1.y; o[6]=x1.z; o[7]=x1.w;
        o[8]=x2.x; o[9]=x2.y; o[10]=x2.z; o[11]=x2.w;
        o[12]=x3.x; o[13]=x3.y; o[14]=x3.z; o[15]=x3.w;
    }
}

// ---------- fast activations (raw HW transcendentals; err ~1e-7 rel) ----------
__device__ __forceinline__ float hw_exp2(float x) {
    float r; asm("v_exp_f32 %0, %1" : "=v"(r) : "v"(x)); return r;
}
__device__ __forceinline__ float hw_rcp(float x) {
    float r; asm("v_rcp_f32 %0, %1" : "=v"(r) : "v"(x)); return r;
}
__device__ __forceinline__ float fast_tanh(float x) {
    float t = hw_exp2(x * 2.88539008177792681f);
    return 1.0f - 2.0f * hw_rcp(t + 1.0f);
}
__device__ __forceinline__ float fast_sigmoid(float x) {
    return hw_rcp(1.0f + hw_exp2(x * -1.44269504088896341f));
}

// ---------- prep: pack W^T hi/lo fp16 per chunk + fp32 triangular ----------
__global__ void prep_kernel(const void* __restrict__ A, const void* __restrict__ B) {
    __shared__ int s_mA, s_wbf;
    if (threadIdx.x == 0) {
        s_mA  = sniff_binary64(A) ? 1 : 0;
        s_wbf = sniff_is_bf16(s_mA ? B : A) ? 1 : 0;
    }
    __syncthreads();
    const int*  maskp = (const int*)(s_mA ? A : B);
    const void* Wp    = s_mA ? B : A;
    const int k = blockIdx.x + 1, j0 = 16 * k, KE = c_KE[k], OFF = c_OFF[k];
    const int tid = threadIdx.x;

    for (int n = 0; n < 16; ++n) {
        const int j = j0 + n;
        for (int kk = tid; kk < KE; kk += 256) {
            const int gi = kk * N_NODES + j;
            float w = 0.0f;
            if (maskp[gi])
                w = s_wbf ? __bfloat162float(((const __hip_bfloat16*)Wp)[gi])
                          : ((const float*)Wp)[gi];
            const _Float16 hi = (_Float16)w;
            const _Float16 lo = (_Float16)(w - (float)hi);
            g_WT[OFF + n * KE + kk]           = hi;
            g_WT[OFF + 16 * KE + n * KE + kk] = lo;
        }
    }
    {   // triangular in-chunk weights, fp32
        const int l = tid >> 4, i = tid & 15;
        const int gi = (j0 + l) * N_NODES + (j0 + i);
        float w = 0.0f;
        if (l < i && maskp[gi])
            w = s_wbf ? __bfloat162float(((const __hip_bfloat16*)Wp)[gi])
                      : ((const float*)Wp)[gi];
        g_Wtri[(k - 1) * 256 + tid] = w;
    }
}

#define MFMA16(a, b, c) __builtin_amdgcn_mfma_f32_16x16x32_f16((a), (b), (c), 0, 0, 0)

// One 16-node chunk, compile-time-indexed, NO scheduling fences.
// vf[q][t]: lane holds A[q*16 + (lane&15)][32t + (lane>>4)*8 .. +8] (fp16, *VSC)
template<int K>
__device__ __forceinline__ void do_chunk(
    const int lane, const long long sg,
    const void* __restrict__ eps, const bool ebf,
    half8 (&vf)[2][8],
    float* __restrict__ Zbuf, _Float16* __restrict__ stag,
    const short* __restrict__ meta,
    float* __restrict__ wsX,
    float* __restrict__ outX, float* __restrict__ outY)
{
    constexpr int j0  = 16 * K;
    constexpr int KE  = KE_tab[K];
    constexpr int NST = KE / 32;
    constexpr int OFF = OFF_tab[K];

    const int mrow = lane & 15;
    const int quad = lane >> 4;

    // eps for this chunk (consumed in tail; scheduler free to hoist/sink)
    float ev[16];
    if (lane < 32)
        load16(eps, sg * (long long)N_COMP + (j0 - N_CAUSES), ebf, ev);

    const _Float16* __restrict__ bp = g_WT + OFF + mrow * KE + (quad << 3);

    f32x4 acc0h = {0.f,0.f,0.f,0.f}, acc0l = {0.f,0.f,0.f,0.f};
    f32x4 acc1h = {0.f,0.f,0.f,0.f}, acc1l = {0.f,0.f,0.f,0.f};

    #pragma unroll
    for (int t = 0; t < NST; ++t) {
        const half8 bh = *(const half8*)(bp + (t << 5));
        const half8 bl = *(const half8*)(bp + 16 * KE + (t << 5));
        acc0h = MFMA16(vf[0][t], bh, acc0h);   // 4 independent chains
        acc1h = MFMA16(vf[1][t], bh, acc1h);
        acc0l = MFMA16(vf[0][t], bl, acc0l);
        acc1l = MFMA16(vf[1][t], bl, acc1l);
    }

    // C-layout (col=mrow = node, row=quad*4+reg = sample) -> Zbuf
    {
        const int r0 = quad << 2;
        #pragma unroll
        for (int r = 0; r < 4; ++r) {
            Zbuf[(r0 + r)      * 21 + mrow] = (acc0h[r] + acc0l[r]) * VSCI;
            Zbuf[(16 + r0 + r) * 21 + mrow] = (acc1h[r] + acc1l[r]) * VSCI;
        }
    }
    // (no fence: LDS ops in-order within the wave; may-alias keeps RAW order)

    // intra-chunk tail, scatter form, branch-free: sample = lane (lanes 0..31)
    if (lane < 32) {
        float zz[16];
        #pragma unroll
        for (int i = 0; i < 16; ++i)
            zz[i] = Zbuf[lane * 21 + i] + NOISE * ev[i];

        const float* __restrict__ tri = g_Wtri + (K - 1) * 256;
        half8 h0, h1;
        if (wsX) {
            #pragma unroll
            for (int i = 0; i < 16; ++i) {
                float z = zz[i];
                const int m = meta[j0 - N_CAUSES + i];     // wave-uniform
                const int a = m & 3;
                const float th = fast_tanh(z);
                const float re = fmaxf(z, 0.0f);
                const float sgm = fast_sigmoid(z);
                z = (a == 1) ? th : (a == 2) ? re : (a == 3) ? sgm : z;
                if (i < 8) h0[i] = (_Float16)(z * VSC);
                else       h1[i - 8] = (_Float16)(z * VSC);
                wsX[((long long)(m >> 2)) * S_LEN + sg] = z;  // unconditional, coalesced
                #pragma unroll
                for (int j = i + 1; j < 16; ++j)
                    zz[j] += tri[(i << 4) + j] * z;
            }
        } else {   // legacy fallback (no workspace)
            #pragma unroll
            for (int i = 0; i < 16; ++i) {
                float z = zz[i];
                const int m = meta[j0 - N_CAUSES + i];
                const int a = m & 3;
                if (a == 1)      z = fast_tanh(z);
                else if (a == 2) z = fmaxf(z, 0.0f);
                else if (a == 3) z = fast_sigmoid(z);
                if (i < 8) h0[i] = (_Float16)(z * VSC);
                else       h1[i - 8] = (_Float16)(z * VSC);
                const int dr = m >> 2;
                if (dr < ROW_Y)       outX[dr] = z;
                else if (dr == ROW_Y) outY[sg] = z;
                #pragma unroll
                for (int j = i + 1; j < 16; ++j)
                    zz[j] += tri[(i << 4) + j] * z;
            }
        }
        *(half8*)(stag + lane * 24)     = h0;
        *(half8*)(stag + lane * 24 + 8) = h1;
    }

    // scatter new 16 node-values into the A-fragment register layout
    constexpr int TT = K >> 1;          // k-window of nodes j0..j0+15
    constexpr int HB = (K & 1) << 1;    // first owning lane-quad (j0%32)/8
    if (quad == HB || quad == HB + 1) {
        const int boff = (quad - HB) << 3;
        #pragma unroll
        for (int q = 0; q < 2; ++q)
            vf[q][TT] = *(const half8*)(stag + (q * 16 + mrow) * 24 + boff);
    }
}

__global__ __launch_bounds__(64, 4)
void scm_kernel(const void* __restrict__ causes,
                const void* __restrict__ eps,
                const int* __restrict__ act_id,
                const void* __restrict__ xidx_raw,
                const int* __restrict__ yidx_raw,
                float* __restrict__ out,
                float* __restrict__ wsX,
                long long ybase) {
    __shared__ __align__(16) float    Zbuf[32 * 21];   // 2688 B
    __shared__ __align__(16) _Float16 stag[32 * 24];   // 1536 B
    __shared__ short meta[N_COMP];                     // 480 B

    const int lane = threadIdx.x;
    const long long sg = (long long)blockIdx.x * 32 + lane;  // valid for lane<32

    // build meta: act | dst<<2  (dst: 0..99 X row, 100 y row, 101 trash)
    for (int t = lane; t < N_COMP; t += 64) meta[t] = -1;
    const unsigned long long* x64 = (const unsigned long long*)xidx_raw;
    const int*                x32 = (const int*)xidx_raw;
    const bool is64 = ((x64[0] >> 32) == 0ull);
    for (int f = lane; f < N_FEAT; f += 64) {
        const int ix = is64 ? (int)x64[f] : x32[f];
        meta[ix - N_CAUSES] = (short)f;            // temp: xp
    }
    const int yi = yidx_raw[0];
    for (int n = lane; n < N_COMP; n += 64) {
        const int xp = meta[n];
        const int dst = (n + N_CAUSES == yi) ? ROW_Y : (xp >= 0 ? xp : ROW_TR);
        meta[n] = (short)((act_id[n] & 3) | (dst << 2));
    }
    const bool cbf = sniff_is_bf16(causes);
    const bool ebf = sniff_is_bf16(eps);

    const int mrow = lane & 15;
    const int quad = lane >> 4;

    // vals in registers: vf[q][t], zero-initialized
    half8 vz;
    #pragma unroll
    for (int e = 0; e < 8; ++e) vz[e] = (_Float16)0.0f;
    half8 vf[2][8];
    #pragma unroll
    for (int q = 0; q < 2; ++q) {
        #pragma unroll
        for (int t = 0; t < 8; ++t) vf[q][t] = vz;
    }

    // causes (nodes 0..15) -> window 0, quads 0/1, via staging scatter
    if (lane < 32) {
        float cv[16];
        load16(causes, sg * (long long)N_CAUSES, cbf, cv);
        half8 c0, c1;
        #pragma unroll
        for (int i = 0; i < 8; ++i) {
            c0[i] = (_Float16)(cv[i] * VSC);
            c1[i] = (_Float16)(cv[8 + i] * VSC);
        }
        *(half8*)(stag + lane * 24)     = c0;
        *(half8*)(stag + lane * 24 + 8) = c1;
    }
    if (quad < 2) {
        #pragma unroll
        for (int q = 0; q < 2; ++q)
            vf[q][0] = *(const half8*)(stag + (q * 16 + mrow) * 24 + (quad << 3));
    }

    float* outX = out + sg * N_FEAT;
    float* outY = out + ybase;

    do_chunk< 1>(lane, sg, eps, ebf, vf, Zbuf, stag, meta, wsX, outX, outY);
    do_chunk< 2>(lane, sg, eps, ebf, vf, Zbuf, stag, meta, wsX, outX, outY);
    do_chunk< 3>(lane, sg, eps, ebf, vf, Zbuf, stag, meta, wsX, outX, outY);
    do_chunk< 4>(lane, sg, eps, ebf, vf, Zbuf, stag, meta, wsX, outX, outY);
    do_chunk< 5>(lane, sg, eps, ebf, vf, Zbuf, stag, meta, wsX, outX, outY);
    do_chunk< 6>(lane, sg, eps, ebf, vf, Zbuf, stag, meta, wsX, outX, outY);
    do_chunk< 7>(lane, sg, eps, ebf, vf, Zbuf, stag, meta, wsX, outX, outY);
    do_chunk< 8>(lane, sg, eps, ebf, vf, Zbuf, stag, meta, wsX, outX, outY);
    do_chunk< 9>(lane, sg, eps, ebf, vf, Zbuf, stag, meta, wsX, outX, outY);
    do_chunk<10>(lane, sg, eps, ebf, vf, Zbuf, stag, meta, wsX, outX, outY);
    do_chunk<11>(lane, sg, eps, ebf, vf, Zbuf, stag, meta, wsX, outX, outY);
    do_chunk<12>(lane, sg, eps, ebf, vf, Zbuf, stag, meta, wsX, outX, outY);
    do_chunk<13>(lane, sg, eps, ebf, vf, Zbuf, stag, meta, wsX, outX, outY);
    do_chunk<14>(lane, sg, eps, ebf, vf, Zbuf, stag, meta, wsX, outX, outY);
    do_chunk<15>(lane, sg, eps, ebf, vf, Zbuf, stag, meta, wsX, outX, outY);
}

// ---------- transpose: ws[100][S] -> out[S][100], plus y row copy ----------
__global__ __launch_bounds__(256)
void xpose_kernel(const float* __restrict__ ws, float* __restrict__ out,
                  long long ybase) {
    __shared__ float tile[64 * 108];   // padded stride (16B-aligned rows)
    const int tid = threadIdx.x;
    const long long s0 = (long long)blockIdx.x * 64;
    // read: 100 features x 16 float4-groups = 1600 float4 (4 samples each)
    #pragma unroll
    for (int g = 0; g < 7; ++g) {
        const int idx = g * 256 + tid;
        if (idx < 1600) {
            const int ff = idx >> 4;       // feature 0..99
            const int sl = idx & 15;       // sample-group
            const float4 v = *(const float4*)(ws + (long long)ff * S_LEN + s0 + sl * 4);
            tile[(sl * 4 + 0) * 108 + ff] = v.x;
            tile[(sl * 4 + 1) * 108 + ff] = v.y;
            tile[(sl * 4 + 2) * 108 + ff] = v.z;
            tile[(sl * 4 + 3) * 108 + ff] = v.w;
        }
    }
    // y row copy (independent of tile)
    if (tid < 16) {
        const float4 v = *(const float4*)(ws + (long long)ROW_Y * S_LEN + s0 + tid * 4);
        *(float4*)(out + ybase + s0 + tid * 4) = v;
    }
    __syncthreads();
    // write: 64 samples x 25 float4 = 1600 float4, contiguous 400B runs
    #pragma unroll
    for (int g = 0; g < 7; ++g) {
        const int idx = g * 256 + tid;
        if (idx < 1600) {
            const int s = idx / 25;
            const int j = idx % 25;
            const float4 v = *(const float4*)(tile + s * 108 + j * 4);
            *(float4*)(out + (s0 + s) * N_FEAT + j * 4) = v;
        }
    }
}

extern "C" void kernel_launch(void* const* d_in, const int* in_sizes, int n_in,
                              void* d_out, int out_size, void* d_ws, size_t ws_size,
                              hipStream_t stream) {
    // resolve inputs by element count (permutation-proof); fall back to dict order
    int ic = 0, iw = 1, ie = 2, im = 3, ia = 4, ix = 5, iy = 6;
    int c = -1, e = -1, a = -1, x = -1, y = -1, m1 = -1, m2 = -1;
    for (int i = 0; i < n_in; ++i) {
        switch (in_sizes[i]) {
            case S_LEN * N_CAUSES:   c = i; break;
            case S_LEN * N_COMP:     e = i; break;
            case N_COMP:             a = i; break;
            case N_FEAT:             x = i; break;
            case 1:                  y = i; break;
            case N_NODES * N_NODES:  (m1 < 0 ? m1 : m2) = i; break;
        }
    }
    if (c >= 0 && e >= 0 && a >= 0 && x >= 0 && y >= 0 && m1 >= 0 && m2 >= 0) {
        ic = c; ie = e; ia = a; ix = x; iy = y; iw = m1; im = m2;
    }

    const void* causes = d_in[ic];
    const void* TA     = d_in[iw];   // one of {W, mask} — device disambiguates
    const void* TB     = d_in[im];
    const void* eps    = d_in[ie];
    const int*  act_id = (const int*)d_in[ia];
    const void* xidx   = d_in[ix];
    const int*  yidx   = (const int*)d_in[iy];
    float*      out    = (float*)d_out;
    const long long ybase = (long long)out_size - S_LEN;

    const bool usews = ws_size >= (size_t)WS_ROWS * S_LEN * sizeof(float);
    float* wsX = usews ? (float*)d_ws : nullptr;

    prep_kernel<<<15, 256, 0, stream>>>(TA, TB);
    scm_kernel<<<S_LEN / 32, 64, 0, stream>>>(causes, eps, act_id, xidx, yidx,
                                              out, wsX, ybase);
    if (usews)
        xpose_kernel<<<S_LEN / 64, 256, 0, stream>>>(wsX, out, ybase);
}

// Round 6
// 371.224 us; speedup vs baseline: 1.0876x; 1.0404x over previous
//
#include <hip/hip_runtime.h>
#include <hip/hip_bf16.h>
#include <hip/hip_fp16.h>

// MLPSCM round 15: cross-chunk B-fragment register prefetch (H1 test).
// Evidence base: dur tracks per-wave t-step count (R11=R12 flat at 172us
// despite 2x occupancy / 2x per-CU VMEM; R13 +41% t-steps -> +30% time;
// R14 +tail work -> +19%). Model: each t-step {load bh,bl -> 4 MFMAs} pays
// full load latency serially because 64-VGPR budget (vf[2][8] = all of it)
// leaves no room to keep B in flight.
// Changes vs R12 (the 172us baseline, restored byte-for-byte otherwise):
//  - B double-buffer in registers: chunk K consumes pre-loaded bc[16],
//    issues chunk K+1's loads into bn[16] BEFORE the tail -> latency hides
//    under tail+LDS round-trip. Only chunk 1's load latency stays exposed.
//  - __launch_bounds__(64,2): ~210 VGPR live (2 wv/SIMD; R11 proved
//    occupancy at this level costs nothing).
//  - R14 regressions reverted: conditional stores, branchy single-activation
//    tail, wave_barriers back (they also pin prefetch placement).

typedef _Float16 half8 __attribute__((ext_vector_type(8)));
typedef float    f32x4 __attribute__((ext_vector_type(4)));

constexpr int S_LEN    = 131072;
constexpr int N_NODES  = 256;
constexpr int N_CAUSES = 16;
constexpr int N_COMP   = 240;
constexpr int N_FEAT   = 100;
constexpr float NOISE  = 0.01f;
constexpr float VSC    = 0.0625f;   // vals store scale 1/16
constexpr float VSCI   = 16.0f;

// K_eff per chunk (K=16k+16 rounded up to 32) and hi/lo-plane pack offsets
constexpr int KE_tab[16]  = {0,32,64,64,96,96,128,128,160,160,192,192,224,224,256,256};
constexpr int OFF_tab[16] = {0,0,1024,3072,5120,8192,11264,15360,19456,24576,29696,
                             35840,41984,49152,56320,64512};

__constant__ int c_KE[16]  = {0,32,64,64,96,96,128,128,160,160,192,192,224,224,256,256};
__constant__ int c_OFF[16] = {0,0,1024,3072,5120,8192,11264,15360,19456,24576,29696,
                              35840,41984,49152,56320,64512};

__device__ _Float16 g_WT[72704];      // per chunk: [hi|lo] planes of [16 cols][KE] W^T
__device__ float    g_Wtri[15 * 256]; // per chunk: [l][i] in-chunk triangular W (fp32)

// ---------- content sniffers ----------
__device__ __forceinline__ bool sniff_binary64(const void* p) {
    const unsigned* u = (const unsigned*)p;
    bool ok = true;
    for (int i = 0; i < 64; ++i) ok = ok && (u[i] <= 1u);
    return ok;
}
__device__ __forceinline__ bool sniff_is_bf16(const void* p) {
    const unsigned* u = (const unsigned*)p;
    bool ok = true;
    for (int i = 0; i < 16; ++i) {
        unsigned e = ((u[i] << 16) >> 23) & 0xffu;
        ok = ok && (e >= 100u) && (e <= 132u);
    }
    return ok;
}
__device__ __forceinline__ float bflo(unsigned u) { return __uint_as_float(u << 16); }
__device__ __forceinline__ float bfhi(unsigned u) { return __uint_as_float(u & 0xffff0000u); }

__device__ __forceinline__ void load16(const void* base, long long off, bool isbf, float* o) {
    if (isbf) {
        const uint4* p = (const uint4*)((const unsigned short*)base + off);
        uint4 a = p[0], b = p[1];
        o[0]=bflo(a.x); o[1]=bfhi(a.x); o[2]=bflo(a.y); o[3]=bfhi(a.y);
        o[4]=bflo(a.z); o[5]=bfhi(a.z); o[6]=bflo(a.w); o[7]=bfhi(a.w);
        o[8]=bflo(b.x); o[9]=bfhi(b.x); o[10]=bflo(b.y); o[11]=bfhi(b.y);
        o[12]=bflo(b.z); o[13]=bfhi(b.z); o[14]=bflo(b.w); o[15]=bfhi(b.w);
    } else {
        const float4* p = (const float4*)((const float*)base + off);
        float4 x0=p[0], x1=p[1], x2=p[2], x3=p[3];
        o[0]=x0.x; o[1]=x0.y; o[2]=x0.z; o[3]=x0.w;
        o[4]=x1.x; o[5]=x1.y; o[6]=x1.z; o[7]=x1.w;
        o[8]=x2.x; o[9]=x2.y; o[10]=x2.z; o[11]=x2.w;
        o[12]=x3.x; o[13]=x3.y; o[14]=x3.z; o[15]=x3.w;
    }
}

// ---------- fast activations (raw HW transcendentals; err ~1e-7 rel) ----------
__device__ __forceinline__ float hw_exp2(float x) {
    float r; asm("v_exp_f32 %0, %1" : "=v"(r) : "v"(x)); return r;
}
__device__ __forceinline__ float hw_rcp(float x) {
    float r; asm("v_rcp_f32 %0, %1" : "=v"(r) : "v"(x)); return r;
}
__device__ __forceinline__ float fast_tanh(float x) {
    float t = hw_exp2(x * 2.88539008177792681f);
    return 1.0f - 2.0f * hw_rcp(t + 1.0f);
}
__device__ __forceinline__ float fast_sigmoid(float x) {
    return hw_rcp(1.0f + hw_exp2(x * -1.44269504088896341f));
}

// ---------- prep: pack W^T hi/lo fp16 per chunk + fp32 triangular ----------
__global__ void prep_kernel(const void* __restrict__ A, const void* __restrict__ B) {
    __shared__ int s_mA, s_wbf;
    if (threadIdx.x == 0) {
        s_mA  = sniff_binary64(A) ? 1 : 0;
        s_wbf = sniff_is_bf16(s_mA ? B : A) ? 1 : 0;
    }
    __syncthreads();
    const int*  maskp = (const int*)(s_mA ? A : B);
    const void* Wp    = s_mA ? B : A;
    const int k = blockIdx.x + 1, j0 = 16 * k, KE = c_KE[k], OFF = c_OFF[k];
    const int tid = threadIdx.x;

    for (int n = 0; n < 16; ++n) {
        const int j = j0 + n;
        for (int kk = tid; kk < KE; kk += 256) {
            const int gi = kk * N_NODES + j;
            float w = 0.0f;
            if (maskp[gi])
                w = s_wbf ? __bfloat162float(((const __hip_bfloat16*)Wp)[gi])
                          : ((const float*)Wp)[gi];
            const _Float16 hi = (_Float16)w;
            const _Float16 lo = (_Float16)(w - (float)hi);
            g_WT[OFF + n * KE + kk]           = hi;
            g_WT[OFF + 16 * KE + n * KE + kk] = lo;
        }
    }
    {   // triangular in-chunk weights, fp32
        const int l = tid >> 4, i = tid & 15;
        const int gi = (j0 + l) * N_NODES + (j0 + i);
        float w = 0.0f;
        if (l < i && maskp[gi])
            w = s_wbf ? __bfloat162float(((const __hip_bfloat16*)Wp)[gi])
                      : ((const float*)Wp)[gi];
        g_Wtri[(k - 1) * 256 + tid] = w;
    }
}

#define MFMA16(a, b, c) __builtin_amdgcn_mfma_f32_16x16x32_f16((a), (b), (c), 0, 0, 0)

// One 16-node chunk, compile-time-indexed, B pre-loaded in registers.
// vf[q][t]: lane holds A[q*16 + (lane&15)][32t + (lane>>4)*8 .. +8] (fp16, *VSC)
// bufA/bufB: [0..7] = hi-plane frags, [8..15] = lo-plane frags.
template<int K>
__device__ __forceinline__ void do_chunk(
    const int lane, const long long sg,
    const void* __restrict__ eps, const bool ebf,
    half8 (&vf)[2][8],
    half8 (&bufA)[16], half8 (&bufB)[16],
    float* __restrict__ Zbuf, _Float16* __restrict__ stag,
    const short* __restrict__ xpos, const int* __restrict__ act_id,
    float* __restrict__ wsX,
    float* __restrict__ outX, float* __restrict__ outY, const int yi)
{
    constexpr int j0  = 16 * K;
    constexpr int KE  = KE_tab[K];
    constexpr int NST = KE / 32;

    const int mrow = lane & 15;
    const int quad = lane >> 4;

    half8 (&bc)[16] = *((K & 1) ? &bufA : &bufB);   // current chunk's B (pre-loaded)
    half8 (&bn)[16] = *((K & 1) ? &bufB : &bufA);   // next chunk's B (fill now)

    // eps for this chunk (consumed in tail -> latency hidden under MFMAs)
    float ev[16];
    if (lane < 32)
        load16(eps, sg * (long long)N_COMP + (j0 - N_CAUSES), ebf, ev);

    f32x4 acc0h = {0.f,0.f,0.f,0.f}, acc0l = {0.f,0.f,0.f,0.f};
    f32x4 acc1h = {0.f,0.f,0.f,0.f}, acc1l = {0.f,0.f,0.f,0.f};

    #pragma unroll
    for (int t = 0; t < NST; ++t) {
        acc0h = MFMA16(vf[0][t], bc[t],     acc0h);   // 4 independent chains
        acc1h = MFMA16(vf[1][t], bc[t],     acc1h);
        acc0l = MFMA16(vf[0][t], bc[8 + t], acc0l);
        acc1l = MFMA16(vf[1][t], bc[8 + t], acc1l);
    }

    // prefetch next chunk's B into the other buffer; its latency hides
    // under the tail + LDS round-trips below (use is after next barrier)
    if constexpr (K < 15) {
        constexpr int KN  = K + 1;
        constexpr int KEn = KE_tab[KN];
        constexpr int NSTn = KEn / 32;
        constexpr int OFFn = OFF_tab[KN];
        const _Float16* __restrict__ bpn = g_WT + OFFn + mrow * KEn + (quad << 3);
        #pragma unroll
        for (int t = 0; t < NSTn; ++t) {
            bn[t]     = *(const half8*)(bpn + (t << 5));
            bn[8 + t] = *(const half8*)(bpn + 16 * KEn + (t << 5));
        }
    }

    // C-layout (col=mrow = node, row=quad*4+reg = sample) -> Zbuf
    {
        const int r0 = quad << 2;
        #pragma unroll
        for (int r = 0; r < 4; ++r) {
            Zbuf[(r0 + r)      * 21 + mrow] = (acc0h[r] + acc0l[r]) * VSCI;
            Zbuf[(16 + r0 + r) * 21 + mrow] = (acc1h[r] + acc1l[r]) * VSCI;
        }
    }
    __builtin_amdgcn_wave_barrier();   // single-wave block: LDS in-order

    // intra-chunk tail, scatter form: sample = lane (lanes 0..31)
    if (lane < 32) {
        float zz[16];
        #pragma unroll
        for (int i = 0; i < 16; ++i)
            zz[i] = Zbuf[lane * 21 + i] + NOISE * ev[i];

        const float* __restrict__ tri = g_Wtri + (K - 1) * 256;
        half8 h0, h1;
        #pragma unroll
        for (int i = 0; i < 16; ++i) {
            float z = zz[i];
            const int a = act_id[j0 - N_CAUSES + i];   // wave-uniform
            if (a == 1)      z = fast_tanh(z);
            else if (a == 2) z = fmaxf(z, 0.0f);
            else if (a == 3) z = fast_sigmoid(z);
            if (i < 8) h0[i] = (_Float16)(z * VSC);
            else       h1[i - 8] = (_Float16)(z * VSC);
            const int xp = xpos[j0 - N_CAUSES + i];    // wave-uniform
            if (xp >= 0) {
                if (wsX) wsX[(long long)xp * S_LEN + sg] = z;  // coalesced
                else     outX[xp] = z;                         // fallback
            }
            if (j0 + i == yi) outY[sg] = z;
            // independent forward updates (same summation order as gather form)
            #pragma unroll
            for (int j = i + 1; j < 16; ++j)
                zz[j] += tri[(i << 4) + j] * z;
        }
        *(half8*)(stag + lane * 24)     = h0;
        *(half8*)(stag + lane * 24 + 8) = h1;
    }
    __builtin_amdgcn_wave_barrier();

    // scatter new 16 node-values into the A-fragment register layout
    constexpr int TT = K >> 1;          // k-window of nodes j0..j0+15
    constexpr int HB = (K & 1) << 1;    // first owning lane-quad (j0%32)/8
    if (quad == HB || quad == HB + 1) {
        const int boff = (quad - HB) << 3;
        #pragma unroll
        for (int q = 0; q < 2; ++q)
            vf[q][TT] = *(const half8*)(stag + (q * 16 + mrow) * 24 + boff);
    }
    __builtin_amdgcn_wave_barrier();
}

__global__ __launch_bounds__(64, 2)
void scm_kernel(const void* __restrict__ causes,
                const void* __restrict__ eps,
                const int* __restrict__ act_id,
                const void* __restrict__ xidx_raw,
                const int* __restrict__ yidx_raw,
                float* __restrict__ out,
                float* __restrict__ wsX,
                long long ybase) {
    __shared__ __align__(16) float    Zbuf[32 * 21];   // 2688 B
    __shared__ __align__(16) _Float16 stag[32 * 24];   // 1536 B
    __shared__ short xpos[N_COMP];                     // 480 B

    const int lane = threadIdx.x;
    const long long sg = (long long)blockIdx.x * 32 + lane;  // valid for lane<32

    for (int t = lane; t < N_COMP; t += 64) xpos[t] = -1;
    const unsigned long long* x64 = (const unsigned long long*)xidx_raw;
    const int*                x32 = (const int*)xidx_raw;
    const bool is64 = ((x64[0] >> 32) == 0ull);
    __builtin_amdgcn_wave_barrier();
    for (int f = lane; f < N_FEAT; f += 64) {
        const int ix = is64 ? (int)x64[f] : x32[f];
        xpos[ix - N_CAUSES] = (short)f;
    }
    __builtin_amdgcn_wave_barrier();
    const int yi  = yidx_raw[0];
    const bool cbf = sniff_is_bf16(causes);
    const bool ebf = sniff_is_bf16(eps);

    const int mrow = lane & 15;
    const int quad = lane >> 4;

    // vals in registers: vf[q][t], zero-initialized
    half8 vz;
    #pragma unroll
    for (int e = 0; e < 8; ++e) vz[e] = (_Float16)0.0f;
    half8 vf[2][8];
    #pragma unroll
    for (int q = 0; q < 2; ++q) {
        #pragma unroll
        for (int t = 0; t < 8; ++t) vf[q][t] = vz;
    }

    // B double-buffers (registers). [0..7]=hi, [8..15]=lo.
    half8 bufA[16], bufB[16];
    #pragma unroll
    for (int t = 0; t < 16; ++t) { bufA[t] = vz; bufB[t] = vz; }

    // prologue: load chunk 1's B (NST=1) into bufA
    {
        const _Float16* __restrict__ bp1 =
            g_WT + OFF_tab[1] + mrow * KE_tab[1] + (quad << 3);
        bufA[0] = *(const half8*)(bp1);
        bufA[8] = *(const half8*)(bp1 + 16 * KE_tab[1]);
    }

    // causes (nodes 0..15) -> window 0, quads 0/1, via staging scatter
    if (lane < 32) {
        float cv[16];
        load16(causes, sg * (long long)N_CAUSES, cbf, cv);
        half8 c0, c1;
        #pragma unroll
        for (int i = 0; i < 8; ++i) {
            c0[i] = (_Float16)(cv[i] * VSC);
            c1[i] = (_Float16)(cv[8 + i] * VSC);
        }
        *(half8*)(stag + lane * 24)     = c0;
        *(half8*)(stag + lane * 24 + 8) = c1;
    }
    __builtin_amdgcn_wave_barrier();
    if (quad < 2) {
        #pragma unroll
        for (int q = 0; q < 2; ++q)
            vf[q][0] = *(const half8*)(stag + (q * 16 + mrow) * 24 + (quad << 3));
    }
    __builtin_amdgcn_wave_barrier();

    float* outX = out + sg * N_FEAT;
    float* outY = out + ybase;

    do_chunk< 1>(lane, sg, eps, ebf, vf, bufA, bufB, Zbuf, stag, xpos, act_id, wsX, outX, outY, yi);
    do_chunk< 2>(lane, sg, eps, ebf, vf, bufA, bufB, Zbuf, stag, xpos, act_id, wsX, outX, outY, yi);
    do_chunk< 3>(lane, sg, eps, ebf, vf, bufA, bufB, Zbuf, stag, xpos, act_id, wsX, outX, outY, yi);
    do_chunk< 4>(lane, sg, eps, ebf, vf, bufA, bufB, Zbuf, stag, xpos, act_id, wsX, outX, outY, yi);
    do_chunk< 5>(lane, sg, eps, ebf, vf, bufA, bufB, Zbuf, stag, xpos, act_id, wsX, outX, outY, yi);
    do_chunk< 6>(lane, sg, eps, ebf, vf, bufA, bufB, Zbuf, stag, xpos, act_id, wsX, outX, outY, yi);
    do_chunk< 7>(lane, sg, eps, ebf, vf, bufA, bufB, Zbuf, stag, xpos, act_id, wsX, outX, outY, yi);
    do_chunk< 8>(lane, sg, eps, ebf, vf, bufA, bufB, Zbuf, stag, xpos, act_id, wsX, outX, outY, yi);
    do_chunk< 9>(lane, sg, eps, ebf, vf, bufA, bufB, Zbuf, stag, xpos, act_id, wsX, outX, outY, yi);
    do_chunk<10>(lane, sg, eps, ebf, vf, bufA, bufB, Zbuf, stag, xpos, act_id, wsX, outX, outY, yi);
    do_chunk<11>(lane, sg, eps, ebf, vf, bufA, bufB, Zbuf, stag, xpos, act_id, wsX, outX, outY, yi);
    do_chunk<12>(lane, sg, eps, ebf, vf, bufA, bufB, Zbuf, stag, xpos, act_id, wsX, outX, outY, yi);
    do_chunk<13>(lane, sg, eps, ebf, vf, bufA, bufB, Zbuf, stag, xpos, act_id, wsX, outX, outY, yi);
    do_chunk<14>(lane, sg, eps, ebf, vf, bufA, bufB, Zbuf, stag, xpos, act_id, wsX, outX, outY, yi);
    do_chunk<15>(lane, sg, eps, ebf, vf, bufA, bufB, Zbuf, stag, xpos, act_id, wsX, outX, outY, yi);
}

// ---------- transpose: ws[100][S] -> out[S][100], float4 both sides ----------
__global__ __launch_bounds__(256)
void xpose_kernel(const float* __restrict__ ws, float* __restrict__ out) {
    __shared__ float tile[64 * 108];   // padded stride (16B-aligned rows)
    const int tid = threadIdx.x;
    const long long s0 = (long long)blockIdx.x * 64;
    // read: 100 features x 16 float4-groups = 1600 float4 (4 samples each)
    #pragma unroll
    for (int g = 0; g < 7; ++g) {
        const int idx = g * 256 + tid;
        if (idx < 1600) {
            const int ff = idx >> 4;       // feature 0..99
            const int sl = idx & 15;       // sample-group
            const float4 v = *(const float4*)(ws + (long long)ff * S_LEN + s0 + sl * 4);
            tile[(sl * 4 + 0) * 108 + ff] = v.x;
            tile[(sl * 4 + 1) * 108 + ff] = v.y;
            tile[(sl * 4 + 2) * 108 + ff] = v.z;
            tile[(sl * 4 + 3) * 108 + ff] = v.w;
        }
    }
    __syncthreads();
    // write: 64 samples x 25 float4 = 1600 float4, contiguous 400B runs
    #pragma unroll
    for (int g = 0; g < 7; ++g) {
        const int idx = g * 256 + tid;
        if (idx < 1600) {
            const int s = idx / 25;
            const int j = idx % 25;
            const float4 v = *(const float4*)(tile + s * 108 + j * 4);
            *(float4*)(out + (s0 + s) * N_FEAT + j * 4) = v;
        }
    }
}

extern "C" void kernel_launch(void* const* d_in, const int* in_sizes, int n_in,
                              void* d_out, int out_size, void* d_ws, size_t ws_size,
                              hipStream_t stream) {
    // resolve inputs by element count (permutation-proof); fall back to dict order
    int ic = 0, iw = 1, ie = 2, im = 3, ia = 4, ix = 5, iy = 6;
    int c = -1, e = -1, a = -1, x = -1, y = -1, m1 = -1, m2 = -1;
    for (int i = 0; i < n_in; ++i) {
        switch (in_sizes[i]) {
            case S_LEN * N_CAUSES:   c = i; break;
            case S_LEN * N_COMP:     e = i; break;
            case N_COMP:             a = i; break;
            case N_FEAT:             x = i; break;
            case 1:                  y = i; break;
            case N_NODES * N_NODES:  (m1 < 0 ? m1 : m2) = i; break;
        }
    }
    if (c >= 0 && e >= 0 && a >= 0 && x >= 0 && y >= 0 && m1 >= 0 && m2 >= 0) {
        ic = c; ie = e; ia = a; ix = x; iy = y; iw = m1; im = m2;
    }

    const void* causes = d_in[ic];
    const void* TA     = d_in[iw];   // one of {W, mask} — device disambiguates
    const void* TB     = d_in[im];
    const void* eps    = d_in[ie];
    const int*  act_id = (const int*)d_in[ia];
    const void* xidx   = d_in[ix];
    const int*  yidx   = (const int*)d_in[iy];
    float*      out    = (float*)d_out;
    const long long ybase = (long long)out_size - S_LEN;

    const bool usews = ws_size >= (size_t)N_FEAT * S_LEN * sizeof(float);
    float* wsX = usews ? (float*)d_ws : nullptr;

    prep_kernel<<<15, 256, 0, stream>>>(TA, TB);
    scm_kernel<<<S_LEN / 32, 64, 0, stream>>>(causes, eps, act_id, xidx, yidx,
                                              out, wsX, ybase);
    if (usews)
        xpose_kernel<<<S_LEN / 64, 256, 0, stream>>>(wsX, out);
}

// Round 7
// 343.683 us; speedup vs baseline: 1.1747x; 1.0801x over previous
//
#include <hip/hip_runtime.h>
#include <hip/hip_bf16.h>
#include <hip/hip_fp16.h>

// MLPSCM round 16: tail operand streams (tri, act) -> LDS.
// R15 post-mortem: compiler sank the B "prefetch" (VGPR 92, not ~200) — H1
// untested; R15 == R12 at half occupancy (+16us).
// Accounting: wall 413k cyc/wave vs ~35k explainable by MFMA/LDS/VALU/B/eps.
// Only population big enough: tail global loads — tri 120/chunk + act 16/chunk
// = ~2040 loads/wave at ~200cy, serialized by SGPR-pressure-limited batching
// inside the zz dependency chain.
// Changes vs R12 (172us reference, otherwise byte-for-byte):
//  - acts[240] staged to LDS in prologue (tail act read = uniform ds_read).
//  - tri double-buffered in LDS trib[2][256]; T14 split: chunk K issues the
//    float4 load of chunk K+1's tri at its top (hides under MFMA section),
//    ds_writes it just before the tail barrier. Tail tri reads = uniform
//    ds_read_b32, broadcast, batchable under one lgkmcnt.
//  - VGPR +4 (one float4); LDS 5.1 -> 7.3 KB (16 blocks/CU OK).

typedef _Float16 half8 __attribute__((ext_vector_type(8)));
typedef float    f32x4 __attribute__((ext_vector_type(4)));

constexpr int S_LEN    = 131072;
constexpr int N_NODES  = 256;
constexpr int N_CAUSES = 16;
constexpr int N_COMP   = 240;
constexpr int N_FEAT   = 100;
constexpr float NOISE  = 0.01f;
constexpr float VSC    = 0.0625f;   // vals store scale 1/16
constexpr float VSCI   = 16.0f;

// K_eff per chunk (K=16k+16 rounded up to 32) and hi/lo-plane pack offsets
constexpr int KE_tab[16]  = {0,32,64,64,96,96,128,128,160,160,192,192,224,224,256,256};
constexpr int OFF_tab[16] = {0,0,1024,3072,5120,8192,11264,15360,19456,24576,29696,
                             35840,41984,49152,56320,64512};

__constant__ int c_KE[16]  = {0,32,64,64,96,96,128,128,160,160,192,192,224,224,256,256};
__constant__ int c_OFF[16] = {0,0,1024,3072,5120,8192,11264,15360,19456,24576,29696,
                              35840,41984,49152,56320,64512};

__device__ _Float16 g_WT[72704];      // per chunk: [hi|lo] planes of [16 cols][KE] W^T
__device__ float    g_Wtri[15 * 256]; // per chunk: [l][i] in-chunk triangular W (fp32)

// ---------- content sniffers ----------
__device__ __forceinline__ bool sniff_binary64(const void* p) {
    const unsigned* u = (const unsigned*)p;
    bool ok = true;
    for (int i = 0; i < 64; ++i) ok = ok && (u[i] <= 1u);
    return ok;
}
__device__ __forceinline__ bool sniff_is_bf16(const void* p) {
    const unsigned* u = (const unsigned*)p;
    bool ok = true;
    for (int i = 0; i < 16; ++i) {
        unsigned e = ((u[i] << 16) >> 23) & 0xffu;
        ok = ok && (e >= 100u) && (e <= 132u);
    }
    return ok;
}
__device__ __forceinline__ float bflo(unsigned u) { return __uint_as_float(u << 16); }
__device__ __forceinline__ float bfhi(unsigned u) { return __uint_as_float(u & 0xffff0000u); }

__device__ __forceinline__ void load16(const void* base, long long off, bool isbf, float* o) {
    if (isbf) {
        const uint4* p = (const uint4*)((const unsigned short*)base + off);
        uint4 a = p[0], b = p[1];
        o[0]=bflo(a.x); o[1]=bfhi(a.x); o[2]=bflo(a.y); o[3]=bfhi(a.y);
        o[4]=bflo(a.z); o[5]=bfhi(a.z); o[6]=bflo(a.w); o[7]=bfhi(a.w);
        o[8]=bflo(b.x); o[9]=bfhi(b.x); o[10]=bflo(b.y); o[11]=bfhi(b.y);
        o[12]=bflo(b.z); o[13]=bfhi(b.z); o[14]=bflo(b.w); o[15]=bfhi(b.w);
    } else {
        const float4* p = (const float4*)((const float*)base + off);
        float4 x0=p[0], x1=p[1], x2=p[2], x3=p[3];
        o[0]=x0.x; o[1]=x0.y; o[2]=x0.z; o[3]=x0.w;
        o[4]=x1.x; o[5]=x1.y; o[6]=x1.z; o[7]=x1.w;
        o[8]=x2.x; o[9]=x2.y; o[10]=x2.z; o[11]=x2.w;
        o[12]=x3.x; o[13]=x3.y; o[14]=x3.z; o[15]=x3.w;
    }
}

// ---------- fast activations (raw HW transcendentals; err ~1e-7 rel) ----------
__device__ __forceinline__ float hw_exp2(float x) {
    float r; asm("v_exp_f32 %0, %1" : "=v"(r) : "v"(x)); return r;
}
__device__ __forceinline__ float hw_rcp(float x) {
    float r; asm("v_rcp_f32 %0, %1" : "=v"(r) : "v"(x)); return r;
}
__device__ __forceinline__ float fast_tanh(float x) {
    float t = hw_exp2(x * 2.88539008177792681f);
    return 1.0f - 2.0f * hw_rcp(t + 1.0f);
}
__device__ __forceinline__ float fast_sigmoid(float x) {
    return hw_rcp(1.0f + hw_exp2(x * -1.44269504088896341f));
}

// ---------- prep: pack W^T hi/lo fp16 per chunk + fp32 triangular ----------
__global__ void prep_kernel(const void* __restrict__ A, const void* __restrict__ B) {
    __shared__ int s_mA, s_wbf;
    if (threadIdx.x == 0) {
        s_mA  = sniff_binary64(A) ? 1 : 0;
        s_wbf = sniff_is_bf16(s_mA ? B : A) ? 1 : 0;
    }
    __syncthreads();
    const int*  maskp = (const int*)(s_mA ? A : B);
    const void* Wp    = s_mA ? B : A;
    const int k = blockIdx.x + 1, j0 = 16 * k, KE = c_KE[k], OFF = c_OFF[k];
    const int tid = threadIdx.x;

    for (int n = 0; n < 16; ++n) {
        const int j = j0 + n;
        for (int kk = tid; kk < KE; kk += 256) {
            const int gi = kk * N_NODES + j;
            float w = 0.0f;
            if (maskp[gi])
                w = s_wbf ? __bfloat162float(((const __hip_bfloat16*)Wp)[gi])
                          : ((const float*)Wp)[gi];
            const _Float16 hi = (_Float16)w;
            const _Float16 lo = (_Float16)(w - (float)hi);
            g_WT[OFF + n * KE + kk]           = hi;
            g_WT[OFF + 16 * KE + n * KE + kk] = lo;
        }
    }
    {   // triangular in-chunk weights, fp32
        const int l = tid >> 4, i = tid & 15;
        const int gi = (j0 + l) * N_NODES + (j0 + i);
        float w = 0.0f;
        if (l < i && maskp[gi])
            w = s_wbf ? __bfloat162float(((const __hip_bfloat16*)Wp)[gi])
                      : ((const float*)Wp)[gi];
        g_Wtri[(k - 1) * 256 + tid] = w;
    }
}

#define MFMA16(a, b, c) __builtin_amdgcn_mfma_f32_16x16x32_f16((a), (b), (c), 0, 0, 0)

// One 16-node chunk, compile-time-indexed.
// vf[q][t]: lane holds A[q*16 + (lane&15)][32t + (lane>>4)*8 .. +8] (fp16, *VSC)
// trib: LDS tri double-buffer; chunk K reads trib[K&1], stages K+1 into
// trib[(K+1)&1] (load issued at top, ds_write before tail barrier).
template<int K>
__device__ __forceinline__ void do_chunk(
    const int lane, const long long sg,
    const void* __restrict__ eps, const bool ebf,
    half8 (&vf)[2][8],
    float* __restrict__ Zbuf, _Float16* __restrict__ stag,
    float (&trib)[2][256],
    const short* __restrict__ xpos, const short* __restrict__ acts,
    float* __restrict__ wsX,
    float* __restrict__ outX, float* __restrict__ outY, const int yi)
{
    constexpr int j0  = 16 * K;
    constexpr int KE  = KE_tab[K];
    constexpr int NST = KE / 32;
    constexpr int OFF = OFF_tab[K];

    const int mrow = lane & 15;
    const int quad = lane >> 4;

    // T14 split: issue next chunk's tri load NOW (consumed as LDS next chunk)
    float4 trv;
    if constexpr (K < 15)
        trv = *(const float4*)(g_Wtri + K * 256 + lane * 4);

    // eps for this chunk (consumed in tail -> latency hidden under MFMAs)
    float ev[16];
    if (lane < 32)
        load16(eps, sg * (long long)N_COMP + (j0 - N_CAUSES), ebf, ev);

    const _Float16* __restrict__ bp = g_WT + OFF + mrow * KE + (quad << 3);

    f32x4 acc0h = {0.f,0.f,0.f,0.f}, acc0l = {0.f,0.f,0.f,0.f};
    f32x4 acc1h = {0.f,0.f,0.f,0.f}, acc1l = {0.f,0.f,0.f,0.f};

    #pragma unroll
    for (int t = 0; t < NST; ++t) {
        const half8 bh = *(const half8*)(bp + (t << 5));
        const half8 bl = *(const half8*)(bp + 16 * KE + (t << 5));
        acc0h = MFMA16(vf[0][t], bh, acc0h);   // 4 independent chains
        acc1h = MFMA16(vf[1][t], bh, acc1h);
        acc0l = MFMA16(vf[0][t], bl, acc0l);
        acc1l = MFMA16(vf[1][t], bl, acc1l);
    }

    // C-layout (col=mrow = node, row=quad*4+reg = sample) -> Zbuf
    {
        const int r0 = quad << 2;
        #pragma unroll
        for (int r = 0; r < 4; ++r) {
            Zbuf[(r0 + r)      * 21 + mrow] = (acc0h[r] + acc0l[r]) * VSCI;
            Zbuf[(16 + r0 + r) * 21 + mrow] = (acc1h[r] + acc1l[r]) * VSCI;
        }
    }
    // write-late half of the tri stage (load latency was hidden by MFMAs)
    if constexpr (K < 15)
        *(float4*)(&trib[(K + 1) & 1][lane * 4]) = trv;
    __builtin_amdgcn_wave_barrier();   // single-wave block: LDS in-order

    // intra-chunk tail, scatter form: sample = lane (lanes 0..31)
    if (lane < 32) {
        float zz[16];
        #pragma unroll
        for (int i = 0; i < 16; ++i)
            zz[i] = Zbuf[lane * 21 + i] + NOISE * ev[i];

        const float* __restrict__ tri = &trib[K & 1][0];   // LDS, uniform reads
        half8 h0, h1;
        #pragma unroll
        for (int i = 0; i < 16; ++i) {
            float z = zz[i];
            const int a = acts[j0 - N_CAUSES + i];     // LDS, uniform broadcast
            if (a == 1)      z = fast_tanh(z);
            else if (a == 2) z = fmaxf(z, 0.0f);
            else if (a == 3) z = fast_sigmoid(z);
            if (i < 8) h0[i] = (_Float16)(z * VSC);
            else       h1[i - 8] = (_Float16)(z * VSC);
            const int xp = xpos[j0 - N_CAUSES + i];    // LDS, uniform broadcast
            if (xp >= 0) {
                if (wsX) wsX[(long long)xp * S_LEN + sg] = z;  // coalesced
                else     outX[xp] = z;                         // fallback
            }
            if (j0 + i == yi) outY[sg] = z;
            // independent forward updates (same summation order as gather form)
            #pragma unroll
            for (int j = i + 1; j < 16; ++j)
                zz[j] += tri[(i << 4) + j] * z;
        }
        *(half8*)(stag + lane * 24)     = h0;
        *(half8*)(stag + lane * 24 + 8) = h1;
    }
    __builtin_amdgcn_wave_barrier();

    // scatter new 16 node-values into the A-fragment register layout
    constexpr int TT = K >> 1;          // k-window of nodes j0..j0+15
    constexpr int HB = (K & 1) << 1;    // first owning lane-quad (j0%32)/8
    if (quad == HB || quad == HB + 1) {
        const int boff = (quad - HB) << 3;
        #pragma unroll
        for (int q = 0; q < 2; ++q)
            vf[q][TT] = *(const half8*)(stag + (q * 16 + mrow) * 24 + boff);
    }
    __builtin_amdgcn_wave_barrier();
}

__global__ __launch_bounds__(64, 4)
void scm_kernel(const void* __restrict__ causes,
                const void* __restrict__ eps,
                const int* __restrict__ act_id,
                const void* __restrict__ xidx_raw,
                const int* __restrict__ yidx_raw,
                float* __restrict__ out,
                float* __restrict__ wsX,
                long long ybase) {
    __shared__ __align__(16) float    Zbuf[32 * 21];   // 2688 B
    __shared__ __align__(16) _Float16 stag[32 * 24];   // 1536 B
    __shared__ __align__(16) float    trib[2][256];    // 2048 B tri double-buffer
    __shared__ short xpos[N_COMP];                     // 480 B
    __shared__ short acts[N_COMP];                     // 480 B

    const int lane = threadIdx.x;
    const long long sg = (long long)blockIdx.x * 32 + lane;  // valid for lane<32

    for (int t = lane; t < N_COMP; t += 64) {
        xpos[t] = -1;
        acts[t] = (short)act_id[t];
    }
    const unsigned long long* x64 = (const unsigned long long*)xidx_raw;
    const int*                x32 = (const int*)xidx_raw;
    const bool is64 = ((x64[0] >> 32) == 0ull);
    __builtin_amdgcn_wave_barrier();
    for (int f = lane; f < N_FEAT; f += 64) {
        const int ix = is64 ? (int)x64[f] : x32[f];
        xpos[ix - N_CAUSES] = (short)f;
    }
    __builtin_amdgcn_wave_barrier();
    const int yi  = yidx_raw[0];
    const bool cbf = sniff_is_bf16(causes);
    const bool ebf = sniff_is_bf16(eps);

    const int mrow = lane & 15;
    const int quad = lane >> 4;

    // stage chunk 1's tri into trib[1]
    {
        const float4 tv = *(const float4*)(g_Wtri + lane * 4);
        *(float4*)(&trib[1][lane * 4]) = tv;
    }

    // vals in registers: vf[q][t], zero-initialized
    half8 vz;
    #pragma unroll
    for (int e = 0; e < 8; ++e) vz[e] = (_Float16)0.0f;
    half8 vf[2][8];
    #pragma unroll
    for (int q = 0; q < 2; ++q) {
        #pragma unroll
        for (int t = 0; t < 8; ++t) vf[q][t] = vz;
    }

    // causes (nodes 0..15) -> window 0, quads 0/1, via staging scatter
    if (lane < 32) {
        float cv[16];
        load16(causes, sg * (long long)N_CAUSES, cbf, cv);
        half8 c0, c1;
        #pragma unroll
        for (int i = 0; i < 8; ++i) {
            c0[i] = (_Float16)(cv[i] * VSC);
            c1[i] = (_Float16)(cv[8 + i] * VSC);
        }
        *(half8*)(stag + lane * 24)     = c0;
        *(half8*)(stag + lane * 24 + 8) = c1;
    }
    __builtin_amdgcn_wave_barrier();
    if (quad < 2) {
        #pragma unroll
        for (int q = 0; q < 2; ++q)
            vf[q][0] = *(const half8*)(stag + (q * 16 + mrow) * 24 + (quad << 3));
    }
    __builtin_amdgcn_wave_barrier();

    float* outX = out + sg * N_FEAT;
    float* outY = out + ybase;

    do_chunk< 1>(lane, sg, eps, ebf, vf, Zbuf, stag, trib, xpos, acts, wsX, outX, outY, yi);
    do_chunk< 2>(lane, sg, eps, ebf, vf, Zbuf, stag, trib, xpos, acts, wsX, outX, outY, yi);
    do_chunk< 3>(lane, sg, eps, ebf, vf, Zbuf, stag, trib, xpos, acts, wsX, outX, outY, yi);
    do_chunk< 4>(lane, sg, eps, ebf, vf, Zbuf, stag, trib, xpos, acts, wsX, outX, outY, yi);
    do_chunk< 5>(lane, sg, eps, ebf, vf, Zbuf, stag, trib, xpos, acts, wsX, outX, outY, yi);
    do_chunk< 6>(lane, sg, eps, ebf, vf, Zbuf, stag, trib, xpos, acts, wsX, outX, outY, yi);
    do_chunk< 7>(lane, sg, eps, ebf, vf, Zbuf, stag, trib, xpos, acts, wsX, outX, outY, yi);
    do_chunk< 8>(lane, sg, eps, ebf, vf, Zbuf, stag, trib, xpos, acts, wsX, outX, outY, yi);
    do_chunk< 9>(lane, sg, eps, ebf, vf, Zbuf, stag, trib, xpos, acts, wsX, outX, outY, yi);
    do_chunk<10>(lane, sg, eps, ebf, vf, Zbuf, stag, trib, xpos, acts, wsX, outX, outY, yi);
    do_chunk<11>(lane, sg, eps, ebf, vf, Zbuf, stag, trib, xpos, acts, wsX, outX, outY, yi);
    do_chunk<12>(lane, sg, eps, ebf, vf, Zbuf, stag, trib, xpos, acts, wsX, outX, outY, yi);
    do_chunk<13>(lane, sg, eps, ebf, vf, Zbuf, stag, trib, xpos, acts, wsX, outX, outY, yi);
    do_chunk<14>(lane, sg, eps, ebf, vf, Zbuf, stag, trib, xpos, acts, wsX, outX, outY, yi);
    do_chunk<15>(lane, sg, eps, ebf, vf, Zbuf, stag, trib, xpos, acts, wsX, outX, outY, yi);
}

// ---------- transpose: ws[100][S] -> out[S][100], float4 both sides ----------
__global__ __launch_bounds__(256)
void xpose_kernel(const float* __restrict__ ws, float* __restrict__ out) {
    __shared__ float tile[64 * 108];   // padded stride (16B-aligned rows)
    const int tid = threadIdx.x;
    const long long s0 = (long long)blockIdx.x * 64;
    // read: 100 features x 16 float4-groups = 1600 float4 (4 samples each)
    #pragma unroll
    for (int g = 0; g < 7; ++g) {
        const int idx = g * 256 + tid;
        if (idx < 1600) {
            const int ff = idx >> 4;       // feature 0..99
            const int sl = idx & 15;       // sample-group
            const float4 v = *(const float4*)(ws + (long long)ff * S_LEN + s0 + sl * 4);
            tile[(sl * 4 + 0) * 108 + ff] = v.x;
            tile[(sl * 4 + 1) * 108 + ff] = v.y;
            tile[(sl * 4 + 2) * 108 + ff] = v.z;
            tile[(sl * 4 + 3) * 108 + ff] = v.w;
        }
    }
    __syncthreads();
    // write: 64 samples x 25 float4 = 1600 float4, contiguous 400B runs
    #pragma unroll
    for (int g = 0; g < 7; ++g) {
        const int idx = g * 256 + tid;
        if (idx < 1600) {
            const int s = idx / 25;
            const int j = idx % 25;
            const float4 v = *(const float4*)(tile + s * 108 + j * 4);
            *(float4*)(out + (s0 + s) * N_FEAT + j * 4) = v;
        }
    }
}

extern "C" void kernel_launch(void* const* d_in, const int* in_sizes, int n_in,
                              void* d_out, int out_size, void* d_ws, size_t ws_size,
                              hipStream_t stream) {
    // resolve inputs by element count (permutation-proof); fall back to dict order
    int ic = 0, iw = 1, ie = 2, im = 3, ia = 4, ix = 5, iy = 6;
    int c = -1, e = -1, a = -1, x = -1, y = -1, m1 = -1, m2 = -1;
    for (int i = 0; i < n_in; ++i) {
        switch (in_sizes[i]) {
            case S_LEN * N_CAUSES:   c = i; break;
            case S_LEN * N_COMP:     e = i; break;
            case N_COMP:             a = i; break;
            case N_FEAT:             x = i; break;
            case 1:                  y = i; break;
            case N_NODES * N_NODES:  (m1 < 0 ? m1 : m2) = i; break;
        }
    }
    if (c >= 0 && e >= 0 && a >= 0 && x >= 0 && y >= 0 && m1 >= 0 && m2 >= 0) {
        ic = c; ie = e; ia = a; ix = x; iy = y; iw = m1; im = m2;
    }

    const void* causes = d_in[ic];
    const void* TA     = d_in[iw];   // one of {W, mask} — device disambiguates
    const void* TB     = d_in[im];
    const void* eps    = d_in[ie];
    const int*  act_id = (const int*)d_in[ia];
    const void* xidx   = d_in[ix];
    const int*  yidx   = (const int*)d_in[iy];
    float*      out    = (float*)d_out;
    const long long ybase = (long long)out_size - S_LEN;

    const bool usews = ws_size >= (size_t)N_FEAT * S_LEN * sizeof(float);
    float* wsX = usews ? (float*)d_ws : nullptr;

    prep_kernel<<<15, 256, 0, stream>>>(TA, TB);
    scm_kernel<<<S_LEN / 32, 64, 0, stream>>>(causes, eps, act_id, xidx, yidx,
                                              out, wsX, ybase);
    if (usews)
        xpose_kernel<<<S_LEN / 64, 256, 0, stream>>>(wsX, out);
}